// Round 5
// baseline (4724.808 us; speedup 1.0000x reference)
//
#include <hip/hip_runtime.h>
#include <hip/hip_bf16.h>

#define T_STEPS 2048
#define HDIM 256
#define VOUT 32000

typedef short short8 __attribute__((ext_vector_type(8)));
typedef float f32x4 __attribute__((ext_vector_type(4)));
typedef int i32x4 __attribute__((ext_vector_type(4)));

#if defined(__has_builtin)
#if __has_builtin(__builtin_amdgcn_rcpf)
#define HAVE_RCP 1
#endif
#endif

__device__ __forceinline__ float fast_rcp(float x) {
#ifdef HAVE_RCP
    return __builtin_amdgcn_rcpf(x);
#else
    return 1.0f / x;
#endif
}
__device__ __forceinline__ float fast_sigmoid(float x) {
    return fast_rcp(1.0f + __expf(-x));
}
__device__ __forceinline__ float fast_tanh(float x) {
    float ax = fabsf(x);
    float e = __expf(-2.0f * ax);
    float t = 1.0f - 2.0f * e * fast_rcp(1.0f + e);
    return copysignf(t, x);
}

// raw barrier: order LDS only; global loads/stores float across (no vmcnt drain)
__device__ __forceinline__ void barrier_lds() {
    asm volatile("s_waitcnt lgkmcnt(0)\n\ts_barrier" ::: "memory");
}

// ---------- quantize a 768x256 fp32 matrix to int8 (per-row scale) ----------
__global__ void k_quant(const float* __restrict__ W, int* __restrict__ wq,
                        float* __restrict__ sc) {
    int row = blockIdx.x;
    int t = threadIdx.x;
    float4 w = ((const float4*)(W + (size_t)row * HDIM))[t];
    float m = fmaxf(fmaxf(fabsf(w.x), fabsf(w.y)), fmaxf(fabsf(w.z), fabsf(w.w)));
#pragma unroll
    for (int off = 32; off; off >>= 1) m = fmaxf(m, __shfl_xor(m, off));
    float inv = (m > 0.0f) ? 127.0f / m : 0.0f;
    float scale = (m > 0.0f) ? m * (1.0f / 127.0f) : 0.0f;
    int q0 = __float2int_rn(w.x * inv); q0 = max(-127, min(127, q0));
    int q1 = __float2int_rn(w.y * inv); q1 = max(-127, min(127, q1));
    int q2 = __float2int_rn(w.z * inv); q2 = max(-127, min(127, q2));
    int q3 = __float2int_rn(w.w * inv); q3 = max(-127, min(127, q3));
    int packed = (q0 & 255) | ((q1 & 255) << 8) | ((q2 & 255) << 16) | ((q3 & 255) << 24);
    wq[row * 64 + t] = packed;
    if (t == 0) sc[row] = scale;
}

// ---------- fp32 -> bf16 (RNE, manual to keep ushort storage) ----------
__global__ __launch_bounds__(256) void k_cvt(const float* __restrict__ in,
                                             unsigned short* __restrict__ out, int n4) {
    int i = blockIdx.x * 256 + threadIdx.x;
    if (i < n4) {
        float4 v = ((const float4*)in)[i];
        unsigned int u[4] = {__float_as_uint(v.x), __float_as_uint(v.y),
                             __float_as_uint(v.z), __float_as_uint(v.w)};
        ushort4 o;
        o.x = (unsigned short)((u[0] + 0x7FFFu + ((u[0] >> 16) & 1)) >> 16);
        o.y = (unsigned short)((u[1] + 0x7FFFu + ((u[1] >> 16) & 1)) >> 16);
        o.z = (unsigned short)((u[2] + 0x7FFFu + ((u[2] >> 16) & 1)) >> 16);
        o.w = (unsigned short)((u[3] + 0x7FFFu + ((u[3] >> 16) & 1)) >> 16);
        ((ushort4*)out)[i] = o;
    }
}

// ---------- Phase A: gi[t][row] = W_ih @ x_t + b_ih (+ b_hh for r/z rows) ----------
__global__ __launch_bounds__(256) void k_gi(const int* __restrict__ toks,
                                            const float* __restrict__ emb,
                                            const float* __restrict__ W,
                                            const float* __restrict__ b,
                                            const float* __restrict__ bhh,
                                            float* __restrict__ gi, int do_relu) {
    __shared__ float4 xs[64];
    int t = blockIdx.x;
    int tid = threadIdx.x;
    int tok = toks[t];
    if (tid < 64) {
        float4 x = ((const float4*)(emb + (size_t)tok * HDIM))[tid];
        if (do_relu) {
            x.x = fmaxf(x.x, 0.0f); x.y = fmaxf(x.y, 0.0f);
            x.z = fmaxf(x.z, 0.0f); x.w = fmaxf(x.w, 0.0f);
        }
        xs[tid] = x;
    }
    __syncthreads();
#pragma unroll
    for (int g = 0; g < 3; ++g) {
        int row = tid + g * 256;
        const float4* wr = (const float4*)(W + (size_t)row * HDIM);
        float acc = b[row] + ((g < 2) ? bhh[row] : 0.0f);
#pragma unroll 16
        for (int k = 0; k < 64; ++k) {
            float4 w = wr[k];
            float4 x = xs[k];
            acc += w.x * x.x + w.y * x.y + w.z * x.z + w.w * x.w;
        }
        gi[(size_t)t * 768 + row] = acc;
    }
}

// ---------- Phase B: sequential double-GRU via i8 MFMA ----------
// The hidden matvec W_hh(768x256) @ h runs on the MATRIX pipe:
// 48 row-tiles(16) x 4 K-tiles(64) = 192 v_mfma_i32_16x16x64_i8 per half-step,
// replacing 192 sdot4/SIMD (the measured VALU-issue bottleneck, invariant
// across R0-R4). B = h broadcast into all 16 cols: B-frag layout
// (col=lane&15, k=(lane>>4)*16+i) is col-independent -> one broadcast
// ds_read_b128 per K-tile. Weights sit in AGPR/VGPR (MFMA reads AGPR
// natively on gfx950 - no copy tax). Integer sums are exact => gate values
// bit-identical to the dot4 version.
// 512 threads = 8 waves; wave w owns row-tiles 6w..6w+5 (rows 96w..96w+95).
// C layout (col=lane&15, row=(lane>>4)*4+reg): lanes with col==0 write the
// raw i32 gate sums to GLDS; after a barrier every lane runs the (unchanged)
// epilogue for element e = tid&255.
__global__ __launch_bounds__(512, 2) void k_gru(
    const int* __restrict__ wq_e, const float* __restrict__ sc_e,
    const float* __restrict__ bhh_e, const float* __restrict__ gi_e,
    const int* __restrict__ wq_d, const float* __restrict__ sc_d,
    const float* __restrict__ bhh_d, const float* __restrict__ gi_d,
    unsigned short* __restrict__ h_bf) {
    __shared__ __align__(16) int HQ[64];     // 256 int8 h values
    __shared__ __align__(16) int GLDS[768];  // raw i32 gate sums

    const int tid = threadIdx.x;
    const int w  = tid >> 6;   // wave 0..7
    const int l  = tid & 63;
    const int lr = l & 15;     // row-in-tile (A) / col (C)
    const int lk = l >> 4;     // k-group
    const int e  = tid & 255;  // epilogue element (2x redundant)

    // A-fragments: wave w, tile j=0..5 -> rows (6w+j)*16 + lr,
    // K-tile kt -> dwords [kt*16 + lk*4, +4)
    i32x4 Ae[6][4], Ad[6][4];
#pragma unroll
    for (int j = 0; j < 6; ++j) {
        const int row = (6 * w + j) * 16 + lr;
#pragma unroll
        for (int kt = 0; kt < 4; ++kt) {
            Ae[j][kt] = *(const i32x4*)(wq_e + row * 64 + kt * 16 + lk * 4);
            Ad[j][kt] = *(const i32x4*)(wq_d + row * 64 + kt * 16 + lk * 4);
        }
    }

    const float se0 = sc_e[e] * (1.0f / 127.0f);
    const float se1 = sc_e[e + 256] * (1.0f / 127.0f);
    const float se2 = sc_e[e + 512] * (1.0f / 127.0f);
    const float sd0 = sc_d[e] * (1.0f / 127.0f);
    const float sd1 = sc_d[e + 256] * (1.0f / 127.0f);
    const float sd2 = sc_d[e + 512] * (1.0f / 127.0f);
    const float be2 = bhh_e[e + 512];
    const float bd2 = bhh_d[e + 512];
    const bool lead = (tid < 256);

    float h = 0.0f;
    if (tid < 64) HQ[tid] = 0;
    __syncthreads();

    const float* ge = gi_e + e;
    const float* gd = gi_d + e;
    unsigned short* hop = h_bf + e;
    const i32x4 z4 = 0;

    // prologue prefetch: encoder gi of step 0
    float eg0 = ge[0], eg1 = ge[256], eg2 = ge[512];

    for (int t = 0; t < T_STEPS; ++t) {
        // prefetch decoder gi of THIS step (consumed ~a half-step from now)
        float dg0 = gd[0], dg1 = gd[256], dg2 = gd[512];
        gd += 768;

        // ---- encoder half ----
        {
            i32x4 B[4];
#pragma unroll
            for (int kt = 0; kt < 4; ++kt)
                B[kt] = *(const i32x4*)(HQ + kt * 16 + lk * 4);
            i32x4 acc[6];
#pragma unroll
            for (int j = 0; j < 6; ++j) {
                i32x4 a = __builtin_amdgcn_mfma_i32_16x16x64_i8(Ae[j][0], B[0], z4, 0, 0, 0);
                a = __builtin_amdgcn_mfma_i32_16x16x64_i8(Ae[j][1], B[1], a, 0, 0, 0);
                a = __builtin_amdgcn_mfma_i32_16x16x64_i8(Ae[j][2], B[2], a, 0, 0, 0);
                acc[j] = __builtin_amdgcn_mfma_i32_16x16x64_i8(Ae[j][3], B[3], a, 0, 0, 0);
            }
            if (lr == 0) {
#pragma unroll
                for (int j = 0; j < 6; ++j)
                    *(i32x4*)(GLDS + (6 * w + j) * 16 + lk * 4) = acc[j];
            }
        }
        barrier_lds();
        {
            float f0 = (float)GLDS[e];
            float f1 = (float)GLDS[e + 256];
            float f2 = (float)GLDS[e + 512];
            float r = fast_sigmoid(eg0 + se0 * f0);
            float z = fast_sigmoid(eg1 + se1 * f1);
            float n = fast_tanh(eg2 + r * (se2 * f2 + be2));
            h = (1.0f - z) * n + z * h;
            if (lead)
                ((signed char*)HQ)[e] = (signed char)__float2int_rn(h * 127.0f);
        }
        barrier_lds();

        // prefetch encoder gi of NEXT step (consumed a full step from now).
        // Last iteration: clamp back inside gi_e (values unused).
        {
            const float* gen = (t < T_STEPS - 1) ? (ge + 768) : (gi_e + e);
            eg0 = gen[0]; eg1 = gen[256]; eg2 = gen[512];
            ge = gen;
        }

        // ---- decoder half ----
        {
            i32x4 B[4];
#pragma unroll
            for (int kt = 0; kt < 4; ++kt)
                B[kt] = *(const i32x4*)(HQ + kt * 16 + lk * 4);
            i32x4 acc[6];
#pragma unroll
            for (int j = 0; j < 6; ++j) {
                i32x4 a = __builtin_amdgcn_mfma_i32_16x16x64_i8(Ad[j][0], B[0], z4, 0, 0, 0);
                a = __builtin_amdgcn_mfma_i32_16x16x64_i8(Ad[j][1], B[1], a, 0, 0, 0);
                a = __builtin_amdgcn_mfma_i32_16x16x64_i8(Ad[j][2], B[2], a, 0, 0, 0);
                acc[j] = __builtin_amdgcn_mfma_i32_16x16x64_i8(Ad[j][3], B[3], a, 0, 0, 0);
            }
            if (lr == 0) {
#pragma unroll
                for (int j = 0; j < 6; ++j)
                    *(i32x4*)(GLDS + (6 * w + j) * 16 + lk * 4) = acc[j];
            }
        }
        barrier_lds();
        {
            float f0 = (float)GLDS[e];
            float f1 = (float)GLDS[e + 256];
            float f2 = (float)GLDS[e + 512];
            float r = fast_sigmoid(dg0 + sd0 * f0);
            float z = fast_sigmoid(dg1 + sd1 * f1);
            float n = fast_tanh(dg2 + r * (sd2 * f2 + bd2));
            h = (1.0f - z) * n + z * h;
            if (lead) {
                ((signed char*)HQ)[e] = (signed char)__float2int_rn(h * 127.0f);
                unsigned int u = __float_as_uint(h);
                *hop = (unsigned short)((u + 0x7FFFu + ((u >> 16) & 1)) >> 16);
            }
            hop += 256;
        }
        barrier_lds();
    }
}

// ---------- Phase C1: logits = H(2048x256) @ out_W^T + b via bf16 MFMA ----------
__global__ __launch_bounds__(256) void k_logits(const unsigned short* __restrict__ hb,
                                                const unsigned short* __restrict__ wb,
                                                const float* __restrict__ out_b,
                                                float* __restrict__ out) {
    const int vb = blockIdx.x * 64;
    const int tb = blockIdx.y * 64;
    const int w = threadIdx.x >> 6;
    const int l = threadIdx.x & 63;
    const int m = l & 15;
    const int q = l >> 4;

    const unsigned short* aptr = hb + (size_t)(tb + w * 16 + m) * HDIM + q * 8;
    const unsigned short* bptr = wb + (size_t)(vb + m) * HDIM + q * 8;

    short8 af[8];
#pragma unroll
    for (int kt = 0; kt < 8; ++kt) af[kt] = *(const short8*)(aptr + kt * 32);

    f32x4 acc[4];
#pragma unroll
    for (int nt = 0; nt < 4; ++nt)
#pragma unroll
        for (int r = 0; r < 4; ++r) acc[nt][r] = 0.0f;

#pragma unroll
    for (int nt = 0; nt < 4; ++nt) {
        const unsigned short* bp = bptr + (size_t)nt * 16 * HDIM;
#pragma unroll
        for (int kt = 0; kt < 8; ++kt) {
            short8 bf = *(const short8*)(bp + kt * 32);
            acc[nt] = __builtin_amdgcn_mfma_f32_16x16x32_bf16(af[kt], bf, acc[nt], 0, 0, 0);
        }
    }
#pragma unroll
    for (int nt = 0; nt < 4; ++nt) {
        float bias = out_b[vb + nt * 16 + m];
#pragma unroll
        for (int r = 0; r < 4; ++r) {
            out[(size_t)(tb + w * 16 + q * 4 + r) * VOUT + vb + nt * 16 + m] =
                acc[nt][r] + bias;
        }
    }
}

// ---------- Phase C2+C3 fused: per-row logsumexp then subtract ----------
__global__ __launch_bounds__(256) void k_lsesub(float* __restrict__ out) {
    const int t = blockIdx.x;
    const int tid = threadIdx.x;
    float* rowp = out + (size_t)t * VOUT;
    float m = -3.0e38f, l = 0.0f;
    for (int v = tid; v < VOUT; v += 256) {
        float x = rowp[v];
        float M = fmaxf(m, x);
        l = l * __expf(m - M) + __expf(x - M);
        m = M;
    }
#pragma unroll
    for (int off = 32; off; off >>= 1) {
        float m2 = __shfl_xor(m, off);
        float l2 = __shfl_xor(l, off);
        float M = fmaxf(m, m2);
        l = l * __expf(m - M) + l2 * __expf(m2 - M);
        m = M;
    }
    __shared__ float sm[4], sl[4];
    __shared__ float s_lse;
    int lane = tid & 63, wv = tid >> 6;
    if (lane == 0) { sm[wv] = m; sl[wv] = l; }
    __syncthreads();
    if (tid == 0) {
        float M = fmaxf(fmaxf(sm[0], sm[1]), fmaxf(sm[2], sm[3]));
        float L = sl[0] * __expf(sm[0] - M) + sl[1] * __expf(sm[1] - M) +
                  sl[2] * __expf(sm[2] - M) + sl[3] * __expf(sm[3] - M);
        s_lse = M + __logf(L);
    }
    __syncthreads();
    float s = s_lse;
    float4* p4 = (float4*)rowp;
    for (int i = tid; i < VOUT / 4; i += 256) {
        float4 o = p4[i];
        o.x -= s; o.y -= s; o.z -= s; o.w -= s;
        p4[i] = o;
    }
}

extern "C" void kernel_launch(void* const* d_in, const int* in_sizes, int n_in,
                              void* d_out, int out_size, void* d_ws, size_t ws_size,
                              hipStream_t stream) {
    (void)in_sizes; (void)n_in; (void)out_size; (void)ws_size;
    const int*   src      = (const int*)d_in[0];
    const int*   trg      = (const int*)d_in[1];
    const float* enc_emb  = (const float*)d_in[2];
    const float* enc_W_ih = (const float*)d_in[3];
    const float* enc_W_hh = (const float*)d_in[4];
    const float* enc_b_ih = (const float*)d_in[5];
    const float* enc_b_hh = (const float*)d_in[6];
    const float* dec_emb  = (const float*)d_in[7];
    const float* dec_W_ih = (const float*)d_in[8];
    const float* dec_W_hh = (const float*)d_in[9];
    const float* dec_b_ih = (const float*)d_in[10];
    const float* dec_b_hh = (const float*)d_in[11];
    const float* out_W    = (const float*)d_in[12];
    const float* out_b    = (const float*)d_in[13];
    float* out = (float*)d_out;

    char* ws = (char*)d_ws;
    float* gi_e  = (float*)ws; ws += (size_t)T_STEPS * 768 * 4;
    float* gi_d  = (float*)ws; ws += (size_t)T_STEPS * 768 * 4;
    float* sc_e  = (float*)ws; ws += 768 * 4;
    float* sc_d  = (float*)ws; ws += 768 * 4;
    int*   wq_e  = (int*)ws;   ws += 768 * 64 * 4;
    int*   wq_d  = (int*)ws;   ws += 768 * 64 * 4;
    unsigned short* h_bf = (unsigned short*)ws; ws += (size_t)T_STEPS * HDIM * 2;
    unsigned short* w_bf = (unsigned short*)ws; ws += (size_t)VOUT * HDIM * 2;

    k_quant<<<768, 64, 0, stream>>>(enc_W_hh, wq_e, sc_e);
    k_quant<<<768, 64, 0, stream>>>(dec_W_hh, wq_d, sc_d);
    k_cvt<<<(VOUT * HDIM / 4 + 255) / 256, 256, 0, stream>>>(out_W, w_bf, VOUT * HDIM / 4);
    k_gi<<<T_STEPS, 256, 0, stream>>>(src, enc_emb, enc_W_ih, enc_b_ih, enc_b_hh, gi_e, 0);
    k_gi<<<T_STEPS, 256, 0, stream>>>(trg, dec_emb, dec_W_ih, dec_b_ih, dec_b_hh, gi_d, 1);
    k_gru<<<1, 512, 0, stream>>>(wq_e, sc_e, enc_b_hh, gi_e,
                                 wq_d, sc_d, dec_b_hh, gi_d, h_bf);
    k_logits<<<dim3(VOUT / 64, T_STEPS / 64), 256, 0, stream>>>(h_bf, w_bf, out_b, out);
    k_lsesub<<<T_STEPS, 256, 0, stream>>>(out);
}

// Round 6
// 4402.132 us; speedup vs baseline: 1.0733x; 1.0733x over previous
//
#include <hip/hip_runtime.h>
#include <hip/hip_bf16.h>

#define T_STEPS 2048
#define HDIM 256
#define VOUT 32000

typedef short short8 __attribute__((ext_vector_type(8)));
typedef float f32x4 __attribute__((ext_vector_type(4)));
typedef int i32x4 __attribute__((ext_vector_type(4)));

// ---------- builtins with fallback ----------
#if defined(__has_builtin)
#if __has_builtin(__builtin_amdgcn_sdot4)
#define HAVE_SDOT4 1
#endif
#if __has_builtin(__builtin_amdgcn_mov_dpp)
#define HAVE_DPP 1
#endif
#if __has_builtin(__builtin_amdgcn_rcpf)
#define HAVE_RCP 1
#endif
#endif

__device__ __forceinline__ int dot4i8(int a, int b, int c) {
#ifdef HAVE_SDOT4
    return __builtin_amdgcn_sdot4(a, b, c, false);
#else
#pragma unroll
    for (int k = 0; k < 4; ++k) {
        int av = (a << (24 - 8 * k)) >> 24;
        int bv = (b << (24 - 8 * k)) >> 24;
        c += av * bv;
    }
    return c;
#endif
}

// keep + (send from lane^1): DPP quad_perm [1,0,3,2]
__device__ __forceinline__ int xor1_add(int keep, int send) {
#ifdef HAVE_DPP
    return keep + __builtin_amdgcn_mov_dpp(send, 0xB1, 0xF, 0xF, true);
#else
    return keep + __shfl_xor(send, 1);
#endif
}
// x + (x from lane^2): DPP quad_perm [2,3,0,1]
__device__ __forceinline__ int xor2_sum(int x) {
#ifdef HAVE_DPP
    return x + __builtin_amdgcn_mov_dpp(x, 0x4E, 0xF, 0xF, true);
#else
    return x + __shfl_xor(x, 2);
#endif
}

__device__ __forceinline__ float fast_rcp(float x) {
#ifdef HAVE_RCP
    return __builtin_amdgcn_rcpf(x);
#else
    return 1.0f / x;
#endif
}
__device__ __forceinline__ float fast_sigmoid(float x) {
    return fast_rcp(1.0f + __expf(-x));
}
__device__ __forceinline__ float fast_tanh(float x) {
    float ax = fabsf(x);
    float e = __expf(-2.0f * ax);
    float t = 1.0f - 2.0f * e * fast_rcp(1.0f + e);
    return copysignf(t, x);
}

// raw barrier: order LDS only; global loads/stores float across (no vmcnt drain)
__device__ __forceinline__ void barrier_lds() {
    asm volatile("s_waitcnt lgkmcnt(0)\n\ts_barrier" ::: "memory");
}

// ---------- quantize a 768x256 fp32 matrix to int8 (per-row scale) ----------
__global__ void k_quant(const float* __restrict__ W, int* __restrict__ wq,
                        float* __restrict__ sc) {
    int row = blockIdx.x;
    int t = threadIdx.x;
    float4 w = ((const float4*)(W + (size_t)row * HDIM))[t];
    float m = fmaxf(fmaxf(fabsf(w.x), fabsf(w.y)), fmaxf(fabsf(w.z), fabsf(w.w)));
#pragma unroll
    for (int off = 32; off; off >>= 1) m = fmaxf(m, __shfl_xor(m, off));
    float inv = (m > 0.0f) ? 127.0f / m : 0.0f;
    float scale = (m > 0.0f) ? m * (1.0f / 127.0f) : 0.0f;
    int q0 = __float2int_rn(w.x * inv); q0 = max(-127, min(127, q0));
    int q1 = __float2int_rn(w.y * inv); q1 = max(-127, min(127, q1));
    int q2 = __float2int_rn(w.z * inv); q2 = max(-127, min(127, q2));
    int q3 = __float2int_rn(w.w * inv); q3 = max(-127, min(127, q3));
    int packed = (q0 & 255) | ((q1 & 255) << 8) | ((q2 & 255) << 16) | ((q3 & 255) << 24);
    wq[row * 64 + t] = packed;
    if (t == 0) sc[row] = scale;
}

// ---------- fp32 -> bf16 (RNE, manual to keep ushort storage) ----------
__global__ __launch_bounds__(256) void k_cvt(const float* __restrict__ in,
                                             unsigned short* __restrict__ out, int n4) {
    int i = blockIdx.x * 256 + threadIdx.x;
    if (i < n4) {
        float4 v = ((const float4*)in)[i];
        unsigned int u[4] = {__float_as_uint(v.x), __float_as_uint(v.y),
                             __float_as_uint(v.z), __float_as_uint(v.w)};
        ushort4 o;
        o.x = (unsigned short)((u[0] + 0x7FFFu + ((u[0] >> 16) & 1)) >> 16);
        o.y = (unsigned short)((u[1] + 0x7FFFu + ((u[1] >> 16) & 1)) >> 16);
        o.z = (unsigned short)((u[2] + 0x7FFFu + ((u[2] >> 16) & 1)) >> 16);
        o.w = (unsigned short)((u[3] + 0x7FFFu + ((u[3] >> 16) & 1)) >> 16);
        ((ushort4*)out)[i] = o;
    }
}

// ---------- Phase A: gi[t][row] = W_ih @ x_t + b_ih (+ b_hh for r/z rows) ----------
__global__ __launch_bounds__(256) void k_gi(const int* __restrict__ toks,
                                            const float* __restrict__ emb,
                                            const float* __restrict__ W,
                                            const float* __restrict__ b,
                                            const float* __restrict__ bhh,
                                            float* __restrict__ gi, int do_relu) {
    __shared__ float4 xs[64];
    int t = blockIdx.x;
    int tid = threadIdx.x;
    int tok = toks[t];
    if (tid < 64) {
        float4 x = ((const float4*)(emb + (size_t)tok * HDIM))[tid];
        if (do_relu) {
            x.x = fmaxf(x.x, 0.0f); x.y = fmaxf(x.y, 0.0f);
            x.z = fmaxf(x.z, 0.0f); x.w = fmaxf(x.w, 0.0f);
        }
        xs[tid] = x;
    }
    __syncthreads();
#pragma unroll
    for (int g = 0; g < 3; ++g) {
        int row = tid + g * 256;
        const float4* wr = (const float4*)(W + (size_t)row * HDIM);
        float acc = b[row] + ((g < 2) ? bhh[row] : 0.0f);
#pragma unroll 16
        for (int k = 0; k < 64; ++k) {
            float4 w = wr[k];
            float4 x = xs[k];
            acc += w.x * x.x + w.y * x.y + w.z * x.z + w.w * x.w;
        }
        gi[(size_t)t * 768 + row] = acc;
    }
}

// ---------- Phase B: sequential double-GRU, hybrid dot4(VALU) + i8 MFMA ----------
// m114: MFMA and VALU pipes co-issue from different waves on one CU.
// Waves 0-3 ("V"): R4's verified dot4+DPP structure, elements 0..127
//   (rows g*256 + [0,128)) -> 96 dot4/lane, in-lane epilogue, no GLDS.
// Waves 4-7 ("M"): R5's verified MFMA fragments, elements 128..255
//   (rows g*256 + [128,256) = 24 16-row tiles, 6/wave x 4 K-MFMAs),
//   raw sums via GLDS, epilogue after barrier A.
// SIMD s hosts waves {s, s+4} = one V + one M wave -> both pipes busy.
// HQ double-buffered (enc: HQA->HQB, dec: HQB->HQA); 2 lgkm-only
// barriers per half-step (A: GLDS written->read; B: HQ complete).
// Integer sums exact on both pipes -> h trajectory bit-identical.
__global__ __launch_bounds__(512, 2) void k_gru(
    const int* __restrict__ wq_e, const float* __restrict__ sc_e,
    const float* __restrict__ bhh_e, const float* __restrict__ gi_e,
    const int* __restrict__ wq_d, const float* __restrict__ sc_d,
    const float* __restrict__ bhh_d, const float* __restrict__ gi_d,
    unsigned short* __restrict__ h_bf) {
    __shared__ __align__(16) int HQA[64];   // h input to encoder half
    __shared__ __align__(16) int HQB[64];   // h input to decoder half
    __shared__ __align__(16) int GLDS[384]; // raw i32 gate sums, elems 128..255

    const int tid = threadIdx.x;
    const bool isV = tid < 256;
    const int l  = tid & 63;
    const int lr = l & 15;   // M: A-row-in-tile / C-col
    const int lk = l >> 4;   // M: k-group
    const int c  = tid & 3;  // V: K-chunk
    const int el = tid & 1;  // V: element parity

    // element this lane runs the epilogue for
    const int eidx = isV ? (2 * (tid >> 2) + el) : (128 + ((tid - 256) & 127));
    const bool duty = isV ? ((tid & 2) == 0) : (tid < 384);

    // weight fragments -- SHARED storage for both paths (192 dwords total)
    i32x4 WE[6][4], WD[6][4];
    int goff[6];
    if (isV) {
        const int q = tid >> 2;
#pragma unroll
        for (int eo = 0; eo < 2; ++eo)
#pragma unroll
            for (int g = 0; g < 3; ++g) {
                const int row = 2 * q + eo + 256 * g;
                const int j = eo * 3 + g;
#pragma unroll
                for (int i = 0; i < 4; ++i) {
                    WE[j][i] = *(const i32x4*)(wq_e + row * 64 + c * 16 + i * 4);
                    WD[j][i] = *(const i32x4*)(wq_d + row * 64 + c * 16 + i * 4);
                }
                goff[j] = 0;
            }
    } else {
        const int mw = (tid >> 6) - 4;
#pragma unroll
        for (int tj = 0; tj < 6; ++tj) {
            const int TJ = mw * 6 + tj;
            const int g = TJ >> 3, s = TJ & 7;
            const int row = 256 * g + 128 + 16 * s + lr;
#pragma unroll
            for (int kt = 0; kt < 4; ++kt) {
                WE[tj][kt] = *(const i32x4*)(wq_e + row * 64 + kt * 16 + lk * 4);
                WD[tj][kt] = *(const i32x4*)(wq_d + row * 64 + kt * 16 + lk * 4);
            }
            goff[tj] = g * 128 + 16 * s + lk * 4;
        }
    }

    const float se0 = sc_e[eidx] * (1.0f / 127.0f);
    const float se1 = sc_e[eidx + 256] * (1.0f / 127.0f);
    const float se2 = sc_e[eidx + 512] * (1.0f / 127.0f);
    const float sd0 = sc_d[eidx] * (1.0f / 127.0f);
    const float sd1 = sc_d[eidx + 256] * (1.0f / 127.0f);
    const float sd2 = sc_d[eidx + 512] * (1.0f / 127.0f);
    const float be2 = bhh_e[eidx + 512];
    const float bd2 = bhh_d[eidx + 512];

    float h = 0.0f;
    if (tid < 64) HQA[tid] = 0;
    __syncthreads();

    const float* ge = gi_e + eidx;
    const float* gd = gi_d + eidx;
    unsigned short* hop = h_bf + eidx;
    const i32x4 z4 = {0, 0, 0, 0};

    // one half-step: read HQr, matvec, epilogue, write HQw (+optional h out)
    auto half = [&](const i32x4(&W)[6][4], float g0, float g1, float g2,
                    float s0, float s1, float s2, float bn,
                    const int* HQr, int* HQw, unsigned short* hout) {
        if (isV) {
            const int4* hq4 = ((const int4*)HQr) + c * 4;
            int p0 = 0, p1 = 0, p2 = 0, p3 = 0, p4 = 0, p5 = 0;
#pragma unroll
            for (int i = 0; i < 4; ++i) {
                int4 v = hq4[i];
                p0 = dot4i8(W[0][i][0], v.x, p0); p0 = dot4i8(W[0][i][1], v.y, p0);
                p0 = dot4i8(W[0][i][2], v.z, p0); p0 = dot4i8(W[0][i][3], v.w, p0);
                p1 = dot4i8(W[1][i][0], v.x, p1); p1 = dot4i8(W[1][i][1], v.y, p1);
                p1 = dot4i8(W[1][i][2], v.z, p1); p1 = dot4i8(W[1][i][3], v.w, p1);
                p2 = dot4i8(W[2][i][0], v.x, p2); p2 = dot4i8(W[2][i][1], v.y, p2);
                p2 = dot4i8(W[2][i][2], v.z, p2); p2 = dot4i8(W[2][i][3], v.w, p2);
                p3 = dot4i8(W[3][i][0], v.x, p3); p3 = dot4i8(W[3][i][1], v.y, p3);
                p3 = dot4i8(W[3][i][2], v.z, p3); p3 = dot4i8(W[3][i][3], v.w, p3);
                p4 = dot4i8(W[4][i][0], v.x, p4); p4 = dot4i8(W[4][i][1], v.y, p4);
                p4 = dot4i8(W[4][i][2], v.z, p4); p4 = dot4i8(W[4][i][3], v.w, p4);
                p5 = dot4i8(W[5][i][0], v.x, p5); p5 = dot4i8(W[5][i][1], v.y, p5);
                p5 = dot4i8(W[5][i][2], v.z, p5); p5 = dot4i8(W[5][i][3], v.w, p5);
            }
            int f0 = xor1_add(el ? p3 : p0, el ? p0 : p3);
            int f1 = xor1_add(el ? p4 : p1, el ? p1 : p4);
            int f2 = xor1_add(el ? p5 : p2, el ? p2 : p5);
            f0 = xor2_sum(f0); f1 = xor2_sum(f1); f2 = xor2_sum(f2);
            float r = fast_sigmoid(g0 + s0 * (float)f0);
            float z = fast_sigmoid(g1 + s1 * (float)f1);
            float n = fast_tanh(g2 + r * (s2 * (float)f2 + bn));
            h = (1.0f - z) * n + z * h;
            if (duty) {
                ((signed char*)HQw)[eidx] = (signed char)__float2int_rn(h * 127.0f);
                if (hout) {
                    unsigned int u = __float_as_uint(h);
                    *hout = (unsigned short)((u + 0x7FFFu + ((u >> 16) & 1)) >> 16);
                }
            }
            barrier_lds();  // A (GLDS written by M)
            barrier_lds();  // B (HQ complete)
        } else {
            i32x4 B0 = *(const i32x4*)(HQr + 0 * 16 + lk * 4);
            i32x4 B1 = *(const i32x4*)(HQr + 1 * 16 + lk * 4);
            i32x4 B2 = *(const i32x4*)(HQr + 2 * 16 + lk * 4);
            i32x4 B3 = *(const i32x4*)(HQr + 3 * 16 + lk * 4);
#pragma unroll
            for (int tj = 0; tj < 6; ++tj) {
                i32x4 a = __builtin_amdgcn_mfma_i32_16x16x64_i8(W[tj][0], B0, z4, 0, 0, 0);
                a = __builtin_amdgcn_mfma_i32_16x16x64_i8(W[tj][1], B1, a, 0, 0, 0);
                a = __builtin_amdgcn_mfma_i32_16x16x64_i8(W[tj][2], B2, a, 0, 0, 0);
                a = __builtin_amdgcn_mfma_i32_16x16x64_i8(W[tj][3], B3, a, 0, 0, 0);
                if (lr == 0) *(i32x4*)(GLDS + goff[tj]) = a;
            }
            barrier_lds();  // A
            const int ep = eidx - 128;
            float f0 = (float)GLDS[ep];
            float f1 = (float)GLDS[128 + ep];
            float f2 = (float)GLDS[256 + ep];
            float r = fast_sigmoid(g0 + s0 * f0);
            float z = fast_sigmoid(g1 + s1 * f1);
            float n = fast_tanh(g2 + r * (s2 * f2 + bn));
            h = (1.0f - z) * n + z * h;
            if (duty) {
                ((signed char*)HQw)[eidx] = (signed char)__float2int_rn(h * 127.0f);
                if (hout) {
                    unsigned int u = __float_as_uint(h);
                    *hout = (unsigned short)((u + 0x7FFFu + ((u >> 16) & 1)) >> 16);
                }
            }
            barrier_lds();  // B
        }
    };

    // prologue prefetch: encoder gi of step 0
    float eg0 = ge[0], eg1 = ge[256], eg2 = ge[512];

    for (int t = 0; t < T_STEPS; ++t) {
        // prefetch decoder gi of THIS step (consumed ~a half-step from now)
        float dg0 = gd[0], dg1 = gd[256], dg2 = gd[512];
        gd += 768;

        // ---- encoder half: HQA -> HQB ----
        half(WE, eg0, eg1, eg2, se0, se1, se2, be2, HQA, HQB, nullptr);

        // prefetch encoder gi of NEXT step (consumed a full step from now).
        // Last iteration: clamp back inside gi_e (values unused).
        {
            const float* gen = (t < T_STEPS - 1) ? (ge + 768) : (gi_e + eidx);
            eg0 = gen[0]; eg1 = gen[256]; eg2 = gen[512];
            ge = gen;
        }

        // ---- decoder half: HQB -> HQA ----
        half(WD, dg0, dg1, dg2, sd0, sd1, sd2, bd2, HQB, HQA, hop);
        hop += 256;
    }
}

// ---------- Phase C1: logits = H(2048x256) @ out_W^T + b via bf16 MFMA ----------
__global__ __launch_bounds__(256) void k_logits(const unsigned short* __restrict__ hb,
                                                const unsigned short* __restrict__ wb,
                                                const float* __restrict__ out_b,
                                                float* __restrict__ out) {
    const int vb = blockIdx.x * 64;
    const int tb = blockIdx.y * 64;
    const int w = threadIdx.x >> 6;
    const int l = threadIdx.x & 63;
    const int m = l & 15;
    const int q = l >> 4;

    const unsigned short* aptr = hb + (size_t)(tb + w * 16 + m) * HDIM + q * 8;
    const unsigned short* bptr = wb + (size_t)(vb + m) * HDIM + q * 8;

    short8 af[8];
#pragma unroll
    for (int kt = 0; kt < 8; ++kt) af[kt] = *(const short8*)(aptr + kt * 32);

    f32x4 acc[4];
#pragma unroll
    for (int nt = 0; nt < 4; ++nt)
#pragma unroll
        for (int r = 0; r < 4; ++r) acc[nt][r] = 0.0f;

#pragma unroll
    for (int nt = 0; nt < 4; ++nt) {
        const unsigned short* bp = bptr + (size_t)nt * 16 * HDIM;
#pragma unroll
        for (int kt = 0; kt < 8; ++kt) {
            short8 bf = *(const short8*)(bp + kt * 32);
            acc[nt] = __builtin_amdgcn_mfma_f32_16x16x32_bf16(af[kt], bf, acc[nt], 0, 0, 0);
        }
    }
#pragma unroll
    for (int nt = 0; nt < 4; ++nt) {
        float bias = out_b[vb + nt * 16 + m];
#pragma unroll
        for (int r = 0; r < 4; ++r) {
            out[(size_t)(tb + w * 16 + q * 4 + r) * VOUT + vb + nt * 16 + m] =
                acc[nt][r] + bias;
        }
    }
}

// ---------- Phase C2+C3 fused: per-row logsumexp then subtract ----------
__global__ __launch_bounds__(256) void k_lsesub(float* __restrict__ out) {
    const int t = blockIdx.x;
    const int tid = threadIdx.x;
    float* rowp = out + (size_t)t * VOUT;
    float m = -3.0e38f, l = 0.0f;
    for (int v = tid; v < VOUT; v += 256) {
        float x = rowp[v];
        float M = fmaxf(m, x);
        l = l * __expf(m - M) + __expf(x - M);
        m = M;
    }
#pragma unroll
    for (int off = 32; off; off >>= 1) {
        float m2 = __shfl_xor(m, off);
        float l2 = __shfl_xor(l, off);
        float M = fmaxf(m, m2);
        l = l * __expf(m - M) + l2 * __expf(m2 - M);
        m = M;
    }
    __shared__ float sm[4], sl[4];
    __shared__ float s_lse;
    int lane = tid & 63, wv = tid >> 6;
    if (lane == 0) { sm[wv] = m; sl[wv] = l; }
    __syncthreads();
    if (tid == 0) {
        float M = fmaxf(fmaxf(sm[0], sm[1]), fmaxf(sm[2], sm[3]));
        float L = sl[0] * __expf(sm[0] - M) + sl[1] * __expf(sm[1] - M) +
                  sl[2] * __expf(sm[2] - M) + sl[3] * __expf(sm[3] - M);
        s_lse = M + __logf(L);
    }
    __syncthreads();
    float s = s_lse;
    float4* p4 = (float4*)rowp;
    for (int i = tid; i < VOUT / 4; i += 256) {
        float4 o = p4[i];
        o.x -= s; o.y -= s; o.z -= s; o.w -= s;
        p4[i] = o;
    }
}

extern "C" void kernel_launch(void* const* d_in, const int* in_sizes, int n_in,
                              void* d_out, int out_size, void* d_ws, size_t ws_size,
                              hipStream_t stream) {
    (void)in_sizes; (void)n_in; (void)out_size; (void)ws_size;
    const int*   src      = (const int*)d_in[0];
    const int*   trg      = (const int*)d_in[1];
    const float* enc_emb  = (const float*)d_in[2];
    const float* enc_W_ih = (const float*)d_in[3];
    const float* enc_W_hh = (const float*)d_in[4];
    const float* enc_b_ih = (const float*)d_in[5];
    const float* enc_b_hh = (const float*)d_in[6];
    const float* dec_emb  = (const float*)d_in[7];
    const float* dec_W_ih = (const float*)d_in[8];
    const float* dec_W_hh = (const float*)d_in[9];
    const float* dec_b_ih = (const float*)d_in[10];
    const float* dec_b_hh = (const float*)d_in[11];
    const float* out_W    = (const float*)d_in[12];
    const float* out_b    = (const float*)d_in[13];
    float* out = (float*)d_out;

    char* ws = (char*)d_ws;
    float* gi_e  = (float*)ws; ws += (size_t)T_STEPS * 768 * 4;
    float* gi_d  = (float*)ws; ws += (size_t)T_STEPS * 768 * 4;
    float* sc_e  = (float*)ws; ws += 768 * 4;
    float* sc_d  = (float*)ws; ws += 768 * 4;
    int*   wq_e  = (int*)ws;   ws += 768 * 64 * 4;
    int*   wq_d  = (int*)ws;   ws += 768 * 64 * 4;
    unsigned short* h_bf = (unsigned short*)ws; ws += (size_t)T_STEPS * HDIM * 2;
    unsigned short* w_bf = (unsigned short*)ws; ws += (size_t)VOUT * HDIM * 2;

    k_quant<<<768, 64, 0, stream>>>(enc_W_hh, wq_e, sc_e);
    k_quant<<<768, 64, 0, stream>>>(dec_W_hh, wq_d, sc_d);
    k_cvt<<<(VOUT * HDIM / 4 + 255) / 256, 256, 0, stream>>>(out_W, w_bf, VOUT * HDIM / 4);
    k_gi<<<T_STEPS, 256, 0, stream>>>(src, enc_emb, enc_W_ih, enc_b_ih, enc_b_hh, gi_e, 0);
    k_gi<<<T_STEPS, 256, 0, stream>>>(trg, dec_emb, dec_W_ih, dec_b_ih, dec_b_hh, gi_d, 1);
    k_gru<<<1, 512, 0, stream>>>(wq_e, sc_e, enc_b_hh, gi_e,
                                 wq_d, sc_d, dec_b_hh, gi_d, h_bf);
    k_logits<<<dim3(VOUT / 64, T_STEPS / 64), 256, 0, stream>>>(h_bf, w_bf, out_b, out);
    k_lsesub<<<T_STEPS, 256, 0, stream>>>(out);
}